// Round 5
// baseline (335.613 us; speedup 1.0000x reference)
//
#include <hip/hip_runtime.h>
#include <hip/hip_bf16.h>
#include <math.h>

#define CIN 128
#define HH 128
#define WW 128
#define HWX (HH*WW)
#define COUT 256
#define NB 4

typedef __attribute__((ext_vector_type(8))) short short8;
typedef __attribute__((ext_vector_type(4))) float f32x4;
typedef __attribute__((ext_vector_type(8))) unsigned short ushort8;

__device__ __forceinline__ unsigned short f2bf(float f) {
    union { float f; unsigned int u; } c; c.f = f;
    unsigned int u = c.u + 0x7FFF + ((c.u >> 16) & 1);   // RNE
    return (unsigned short)(u >> 16);
}
__device__ __forceinline__ float bf2f(unsigned short u) {
    union { unsigned int u; float f; } c; c.u = ((unsigned int)u) << 16;
    return c.f;
}

// ---------------------------------------------------------------------------
// Prep 1: pack offset/mod conv weights contiguously: wofft[c][t][28]
// ---------------------------------------------------------------------------
__global__ __launch_bounds__(256) void wpack_kernel(
    const float* __restrict__ offw, const float* __restrict__ modw,
    float* __restrict__ wofft)
{
    int i = blockIdx.x * 256 + threadIdx.x;
    if (i >= CIN * 9 * 28) return;
    int o = i % 28;
    int t = (i / 28) % 9;
    int c = i / 252;
    float v = 0.f;
    if (o < 18)      v = offw[(o * CIN + c) * 9 + t];
    else if (o < 27) v = modw[((o - 18) * CIN + c) * 9 + t];
    wofft[i] = v;
}

// ---------------------------------------------------------------------------
// Prep 2: bf16 A-fragment image (layout verified R2-R4).
//   L = ((c36*16 + mt)*64 + l)*8 + j ; o = mt*16+(l&15); c = cc*32+(l>>4)*8+j
// ---------------------------------------------------------------------------
__global__ __launch_bounds__(256) void wimg_kernel(
    const float* __restrict__ wgt, unsigned short* __restrict__ wAi)
{
    int i = blockIdx.x * 256 + threadIdx.x;   // < 294912
    int j  = i & 7;
    int l  = (i >> 3) & 63;
    int mt = (i >> 9) & 15;
    int cc = (i >> 13) & 3;
    int kk = i >> 15;
    int o = mt * 16 + (l & 15);
    int c = cc * 32 + (l >> 4) * 8 + j;
    wAi[i] = f2bf(wgt[(o * CIN + c) * 9 + kk]);
}

// ---------------------------------------------------------------------------
// Prep 3: NCHW -> NHWC fp32 transpose of x.
//   xT[((b*128 + y)*128 + x)*128 + c]
// ---------------------------------------------------------------------------
__global__ __launch_bounds__(256) void xt_kernel(
    const float* __restrict__ x, float* __restrict__ xT)
{
    __shared__ float ls[32][132];
    const int tid = threadIdx.x;
    const int bz = blockIdx.x;                // b*512 + y*4 + cg
    const int cg = bz & 3;
    const int y  = (bz >> 2) & 127;
    const int b  = bz >> 9;
    {
        int c  = tid >> 3;                    // 0..31
        int x0 = (tid & 7) << 4;              // 0,16,..,112
        const float* src = x + (((size_t)(b * CIN + (cg << 5) + c)) << 14) + (y << 7) + x0;
#pragma unroll
        for (int k = 0; k < 4; ++k)
            *(f32x4*)&ls[c][x0 + 4 * k] = *(const f32x4*)(src + 4 * k);
    }
    __syncthreads();
    {
        int xc = tid >> 1;                    // 0..127
        int h  = tid & 1;                     // 16-ch half
        float v[16];
#pragma unroll
        for (int j = 0; j < 16; ++j) v[j] = ls[h * 16 + j][xc];
        float* dst = xT + ((((size_t)((b << 7) + y) << 7) + xc) << 7) + (cg << 5) + (h << 4);
#pragma unroll
        for (int k = 0; k < 4; ++k) {
            f32x4 t = { v[4 * k], v[4 * k + 1], v[4 * k + 2], v[4 * k + 3] };
            *(f32x4*)(dst + 4 * k) = t;
        }
    }
}

// ---------------------------------------------------------------------------
// Kernel A1: partial offset/mask conv, 16-channel chunks (8-way split).
// ---------------------------------------------------------------------------
__global__ __launch_bounds__(256) void convpart_kernel(
    const float* __restrict__ x, const float* __restrict__ wofft,
    unsigned short* __restrict__ part)
{
    __shared__ float xs[8][10][34];

    const int tid = threadIdx.x;
    const int lx = tid & 31, ly = tid >> 5;
    const int z = blockIdx.z;               // b*8 + chunk
    const int b = z >> 3, chunk = z & 7;
    const int cbase = chunk * 16;
    const int ty0 = blockIdx.y * 8;
    const int tx0 = blockIdx.x * 32;
    const int ho = ty0 + ly, wo = tx0 + lx;

    float acc[27];
#pragma unroll
    for (int o = 0; o < 27; ++o) acc[o] = 0.f;

#pragma unroll 1
    for (int c0 = 0; c0 < 16; c0 += 8) {
        for (int e = tid; e < 8 * 10 * 34; e += 256) {
            int c = e / 340;
            int rem = e - c * 340;
            int r = rem / 34;
            int col = rem - r * 34;
            int gy = ty0 + r - 1, gx = tx0 + col - 1;
            float v = 0.f;
            if (gy >= 0 && gy < HH && gx >= 0 && gx < WW)
                v = x[(((b * CIN) + (cbase + c0 + c)) << 14) + (gy << 7) + gx];
            xs[c][r][col] = v;
        }
        __syncthreads();

#pragma unroll 1
        for (int c = 0; c < 8; ++c) {
            float xv[3][3];
#pragma unroll
            for (int dy = 0; dy < 3; ++dy)
#pragma unroll
                for (int dx = 0; dx < 3; ++dx)
                    xv[dy][dx] = xs[c][ly + dy][lx + dx];
#pragma unroll
            for (int t = 0; t < 9; ++t) {
                const float* wp = wofft + ((cbase + c0 + c) * 9 + t) * 28;
                float xt = xv[t / 3][t % 3];
#pragma unroll
                for (int o = 0; o < 27; ++o)
                    acc[o] = fmaf(xt, wp[o], acc[o]);
            }
        }
        __syncthreads();
    }

    const int pix = (ho << 7) + wo;
    unsigned short* pp = part + ((z * 27) << 14) + pix;
#pragma unroll
    for (int o = 0; o < 27; ++o)
        pp[o << 14] = f2bf(acc[o]);
}

// ---------------------------------------------------------------------------
// Kernel A2: combine 8 partials + sampling-table epilogue.
// ---------------------------------------------------------------------------
__global__ __launch_bounds__(256) void tables_kernel(
    const unsigned short* __restrict__ part, const float* __restrict__ offb,
    const float* __restrict__ modb,
    unsigned int* __restrict__ pk_out, float4* __restrict__ w4_out)
{
    const int gid = blockIdx.x * 256 + threadIdx.x;
    const int pix = gid & 16383;
    const int t = gid >> 14;                // b*9 + kk
    const int kk = t % 9;
    const int b = t / 9;
    const int ho = pix >> 7, wo = pix & 127;

    float oy = 0.f, ox = 0.f, mt = 0.f;
#pragma unroll
    for (int ch = 0; ch < 8; ++ch) {
        const unsigned short* pp = part + (((b * 8 + ch) * 27) << 14) + pix;
        oy += bf2f(pp[(2 * kk) << 14]);
        ox += bf2f(pp[(2 * kk + 1) << 14]);
        mt += bf2f(pp[(18 + kk) << 14]);
    }
    oy += offb[2 * kk];
    ox += offb[2 * kk + 1];
    mt += modb[kk];

    float m = 2.f / (1.f + expf(-mt));
    float py = (float)(ho - 1 + kk / 3) + oy;
    float px = (float)(wo - 1 + kk % 3) + ox;
    float y0f = floorf(py), x0f = floorf(px);
    float wy = py - y0f, wx = px - x0f;
    int y0 = (int)y0f, x0 = (int)x0f;
    int y1 = y0 + 1, x1 = x0 + 1;
    float vy0 = (y0 >= 0 && y0 < HH) ? 1.f : 0.f;
    float vy1 = (y1 >= 0 && y1 < HH) ? 1.f : 0.f;
    float vx0 = (x0 >= 0 && x0 < WW) ? 1.f : 0.f;
    float vx1 = (x1 >= 0 && x1 < WW) ? 1.f : 0.f;
    float a  = m * (1.f - wy) * vy0;
    float bb = m * wy * vy1;
    float u  = (1.f - wx) * vx0;
    float vv = wx * vx1;
    int y0c = min(max(y0, 0), HH - 1), y1c = min(max(y1, 0), HH - 1);
    int x0c = min(max(x0, 0), WW - 1), x1c = min(max(x1, 0), WW - 1);
    int cb = min(max(x0, 0), WW - 2);
    float wl = ((x0c == cb) ? u : 0.f) + ((x1c == cb) ? vv : 0.f);
    float wr = ((x0c == cb + 1) ? u : 0.f) + ((x1c == cb + 1) ? vv : 0.f);
    unsigned int pkv = (unsigned)y0c | ((unsigned)y1c << 7) |
                       ((unsigned)cb << 14);
    pk_out[gid] = pkv;
    w4_out[gid] = make_float4(a * wl, a * wr, bb * wl, bb * wr);
}

// ---------------------------------------------------------------------------
// Kernel G (R5): ideal-pattern gather + L2-resident banding.
// R4 counters: FETCH 23->130 MB -- the 64-row band (66x64KB=4.3MB) + 147MB
// write stream overflows the 4MiB per-XCD L2; xT re-fetched ~4x from HBM.
// Fix: 32-row quarter-bands, 8 bands (one per XCD) per PASS, two sequential
// passes. Per-XCD footprint ~34 rows x 64KB = 2.2MB -> L2-resident.
// Arithmetic/layout/precision identical to R4 (exact numerics).
// ---------------------------------------------------------------------------
__global__ __launch_bounds__(256) void gather_kernel(
    const float* __restrict__ xT, const unsigned int* __restrict__ pk,
    const float4* __restrict__ w4, unsigned short* __restrict__ samp,
    int b0, int p0, int nbp)
{
    __shared__ unsigned char glds[4096];      // 4 waves x 1 KB
    const int tid = threadIdx.x;
    const int wave = tid >> 6;
    const int l = tid & 63;
    unsigned char* wb = glds + (wave << 10);

    const int F = blockIdx.x;
    const int bandl = F % nbp;                // XCD-aligned band slot
    const int bandg = p0 + bandl;             // global band = lb*4 + yq
    const int lb = bandg >> 2;
    const int yq = bandg & 3;                 // 32-row quarter
    const int b = b0 + lb;
    const int s = F / nbp;                    // 0..127
    const int unit = s * 4 + wave;            // 0..511
    const int h = unit & 1;                   // pixel-half of the 16-px group
    const int gb = unit >> 1;                 // 0..255
    const int row = (yq << 5) + (gb >> 3);
    const int gx16 = gb & 7;
    const int g = (lb << 10) + (row << 3) + gx16;
    const float* xb = xT + ((size_t)b << 21);
    unsigned short* sg0 = samp + (((size_t)g * 36) << 9);
    const float colf = (l >= 32) ? 1.f : 0.f;

    // lane (l&7) holds the sampling table entry for its pixel of this wave's 8
    int gi = ((b * 9) << 14) + (row << 7) + (gx16 << 4) + (h << 3) + (l & 7);
    unsigned int tpk = pk[gi];
    float4 tw = w4[gi];

#pragma unroll 1
    for (int kk = 0; kk < 9; ++kk) {
        // prefetch next kk's tables (clamped at kk==8)
        int gin = gi + ((kk < 8) ? 16384 : 0);
        unsigned int tpkn = pk[gin];
        float4 twn = w4[gin];

#pragma unroll
        for (int st = 0; st < 2; ++st) {
            f32x4 r0[4], r1[4];
            float cw0[4], cw1[4];
#pragma unroll
            for (int p = 0; p < 4; ++p) {
                const int idx = st * 4 + p;
                unsigned int pv = __shfl(tpk, idx);
                float wx_ = __shfl(tw.x, idx);
                float wy_ = __shfl(tw.y, idx);
                float wz_ = __shfl(tw.z, idx);
                float ww_ = __shfl(tw.w, idx);
                cw0[p] = fmaf(wy_ - wx_, colf, wx_);   // row y0 col weight
                cw1[p] = fmaf(ww_ - wz_, colf, wz_);   // row y1 col weight
                const int y0c = pv & 127;
                const int y1c = (pv >> 7) & 127;
                const int cb  = pv >> 14;              // [0,126]
                // 1024 B contiguous: cols cb, cb+1 x 128 ch; lane l -> 16 B
                const float* base0 = xb + ((((y0c << 7) + cb) << 7) + (l << 2));
                const float* base1 = xb + ((((y1c << 7) + cb) << 7) + (l << 2));
                r0[p] = *(const f32x4*)base0;
                r1[p] = *(const f32x4*)base1;
            }
#pragma unroll
            for (int p = 0; p < 4; ++p) {
                float res[4];
#pragma unroll
                for (int j = 0; j < 4; ++j) {
                    float t = r0[p][j] * cw0[p] + r1[p][j] * cw1[p];
                    res[j] = t + __shfl_xor(t, 32);    // add other column
                }
                unsigned int d0 = (unsigned int)f2bf(res[0]) |
                                  ((unsigned int)f2bf(res[1]) << 16);
                unsigned int d1 = (unsigned int)f2bf(res[2]) |
                                  ((unsigned int)f2bf(res[3]) << 16);
                uint2 dd; dd.x = d0; dd.y = d1;
                // lanes l and l+32 hold identical data; both write same bytes
                *(uint2*)(wb + (p << 8) + ((l & 31) << 3)) = dd;
            }
            // wave-synchronous repack: quad (l&31) -> octet chunks
            ushort8 chunk = *(ushort8*)(wb + ((l >> 4) << 8) + ((l & 15) << 4));
            const int px = (h << 3) + (st << 2) + (l >> 4); // pixel in group
            const int cc = (l & 15) >> 2;
            const int q  = l & 3;
            *(ushort8*)&sg0[((((kk << 2) + cc) << 6) + (q << 4) + px) << 3] =
                chunk;
        }
        tpk = tpkn; tw = twn;
        gi += 16384;
    }
}

// ---------------------------------------------------------------------------
// Kernel B: clean MFMA GEMM (R1 version -- NT reverted; it cost +45 us in R2).
// ---------------------------------------------------------------------------
__global__ __launch_bounds__(256) void dgemm_kernel(
    const unsigned short* __restrict__ wAi,
    const unsigned short* __restrict__ samp,
    float* __restrict__ out, int b0)
{
    const int tid = threadIdx.x;
    const int wave = tid >> 6;
    const int l = tid & 63;
    const int bx = blockIdx.x;
    const int lb = bx >> 8;
    const int b = b0 + lb;
    const int seg = bx & 255;
    const int pix0 = seg << 6;
    const unsigned short* sb =
        samp + (((size_t)((lb << 10) + (seg << 2)) * 36) << 9) + (l << 3);
    const int NTS = 36 << 9;                // nt stride in shorts

    f32x4 acc[4][4];
#pragma unroll
    for (int i = 0; i < 4; ++i)
#pragma unroll
        for (int j = 0; j < 4; ++j) acc[i][j] = (f32x4){0.f, 0.f, 0.f, 0.f};

    short8 bf[4], bfn[4];
#pragma unroll
    for (int nt = 0; nt < 4; ++nt)
        bf[nt] = *(const short8*)(sb + nt * NTS);

#pragma unroll 1
    for (int c36 = 0; c36 < 36; ++c36) {
        // A fragments (oldest in vmcnt order)
        const unsigned short* ap = wAi + (c36 << 13) + (wave << 11) + (l << 3);
        short8 af[4];
#pragma unroll
        for (int mt = 0; mt < 4; ++mt)
            af[mt] = *(const short8*)(ap + (mt << 9));

        // prefetch next chunk's B (stays in flight across MFMAs)
        int cn = (c36 < 35) ? c36 + 1 : 35;
#pragma unroll
        for (int nt = 0; nt < 4; ++nt)
            bfn[nt] = *(const short8*)(sb + nt * NTS + (cn << 9));

#pragma unroll
        for (int mt = 0; mt < 4; ++mt)
#pragma unroll
            for (int nt = 0; nt < 4; ++nt)
                acc[mt][nt] = __builtin_amdgcn_mfma_f32_16x16x32_bf16(
                    af[mt], bf[nt], acc[mt][nt], 0, 0, 0);

#pragma unroll
        for (int nt = 0; nt < 4; ++nt) bf[nt] = bfn[nt];
    }

    // epilogue: C/D col=lane&15 (=px), row=(lane>>4)*4+reg (verified R2-R4)
    const int crow = (l >> 4) * 4;
    const int pxl = pix0 + (l & 15);
#pragma unroll
    for (int mt = 0; mt < 4; ++mt) {
#pragma unroll
        for (int nt = 0; nt < 4; ++nt) {
#pragma unroll
            for (int r = 0; r < 4; ++r) {
                int o = wave * 64 + mt * 16 + crow + r;
                out[(((size_t)(b * COUT + o)) << 14) + pxl + nt * 16] =
                    acc[mt][nt][r];
            }
        }
    }
}

// ---------------------------------------------------------------------------
extern "C" void kernel_launch(void* const* d_in, const int* in_sizes, int n_in,
                              void* d_out, int out_size, void* d_ws, size_t ws_size,
                              hipStream_t stream)
{
    const float* x    = (const float*)d_in[0];
    const float* offw = (const float*)d_in[1];
    const float* offb = (const float*)d_in[2];
    const float* modw = (const float*)d_in[3];
    const float* modb = (const float*)d_in[4];
    const float* wgt  = (const float*)d_in[5];
    float* out = (float*)d_out;

    char* wsb = (char*)d_ws;
    unsigned int*   pkp   = (unsigned int*)wsb;                    //  2,359,296 B
    float4*         w4p   = (float4*)(wsb + 2359296);              //  9,437,184 B
    unsigned short* wAi   = (unsigned short*)(wsb + 11796480);     //    589,824 B
    float*          wofft = (float*)(wsb + 12386304);              //    129,024 B
    float*          xTp   = (float*)(wsb + 12515328);              // 33,554,432 B (persistent NHWC image)
    const size_t persistX = 12515328 + 33554432;                   // 46,069,760
    unsigned short* part  = (unsigned short*)(wsb + persistX);     // 28,311,552 B
    unsigned short* samp  = (unsigned short*)(wsb + persistX);     // reuses part region
    const size_t SAMP1 = 37748736;   // bytes per batch of samp

    // pick largest batch-group that fits: samp overlaps dead part buffer
    int nb = 4;
    if (ws_size < persistX + 4 * SAMP1) nb = 2;
    if (ws_size < persistX + 2 * SAMP1) nb = 1;
    // conv phase needs persistX + 28.3MB <= persistX + 1*SAMP1

    wpack_kernel<<<dim3((CIN * 9 * 28 + 255) / 256), 256, 0, stream>>>(offw, modw, wofft);
    wimg_kernel<<<dim3(COUT * CIN * 9 / 256), 256, 0, stream>>>(wgt, wAi);
    xt_kernel<<<dim3(NB * 128 * 4), 256, 0, stream>>>(x, xTp);
    convpart_kernel<<<dim3(WW / 32, HH / 8, NB * 8), 256, 0, stream>>>(x, wofft, part);
    tables_kernel<<<dim3(NB * 9 * HWX / 256), 256, 0, stream>>>(part, offb, modb, pkp, w4p);

    for (int b0 = 0; b0 < NB; b0 += nb) {
        const int nbands = nb * 4;           // 32-row quarter-bands
        for (int p0 = 0; p0 < nbands; p0 += 8) {
            int nbp = (nbands - p0 < 8) ? (nbands - p0) : 8;
            gather_kernel<<<dim3(nbp * 128), 256, 0, stream>>>(
                xTp, pkp, w4p, samp, b0, p0, nbp);
        }
        dgemm_kernel<<<dim3(nb * 256), 256, 0, stream>>>(wAi, samp, out, b0);
    }
}

// Round 6
// 281.624 us; speedup vs baseline: 1.1917x; 1.1917x over previous
//
#include <hip/hip_runtime.h>
#include <hip/hip_bf16.h>
#include <math.h>

#define CIN 128
#define HH 128
#define WW 128
#define HWX (HH*WW)
#define COUT 256
#define NB 4

typedef __attribute__((ext_vector_type(8))) short short8;
typedef __attribute__((ext_vector_type(4))) float f32x4;
typedef __attribute__((ext_vector_type(8))) unsigned short ushort8;

__device__ __forceinline__ unsigned short f2bf(float f) {
    union { float f; unsigned int u; } c; c.f = f;
    unsigned int u = c.u + 0x7FFF + ((c.u >> 16) & 1);   // RNE
    return (unsigned short)(u >> 16);
}
__device__ __forceinline__ float bf2f(unsigned short u) {
    union { unsigned int u; float f; } c; c.u = ((unsigned int)u) << 16;
    return c.f;
}

// ---------------------------------------------------------------------------
// Prep 1: bf16 A-fragment image for the big GEMM (layout verified R2-R4).
//   L = ((c36*16 + mt)*64 + l)*8 + j ; o = mt*16+(l&15); c = cc*32+(l>>4)*8+j
// ---------------------------------------------------------------------------
__global__ __launch_bounds__(256) void wimg_kernel(
    const float* __restrict__ wgt, unsigned short* __restrict__ wAi)
{
    int i = blockIdx.x * 256 + threadIdx.x;   // < 294912
    int j  = i & 7;
    int l  = (i >> 3) & 63;
    int mt = (i >> 9) & 15;
    int cc = (i >> 13) & 3;
    int kk = i >> 15;
    int o = mt * 16 + (l & 15);
    int c = cc * 32 + (l >> 4) * 8 + j;
    wAi[i] = f2bf(wgt[(o * CIN + c) * 9 + kk]);
}

// ---------------------------------------------------------------------------
// Prep 2 (NEW): bf16 A-fragment image for the offset/mod conv GEMM.
//   27 outputs padded to 32 (2 MFMA row-tiles); K = t*128 + c, 36 chunks.
//   wCi[((q36*2 + mt)*64 + l)*8 + j]: o = mt*16+(l&15),
//   c = (q36&3)*32+(l>>4)*8+j, t = q36>>2.  36864 elems = 72 KB.
// ---------------------------------------------------------------------------
__global__ __launch_bounds__(256) void wcimg_kernel(
    const float* __restrict__ offw, const float* __restrict__ modw,
    unsigned short* __restrict__ wCi)
{
    int i = blockIdx.x * 256 + threadIdx.x;   // < 36864
    if (i >= 36864) return;
    int j   = i & 7;
    int l   = (i >> 3) & 63;
    int mt  = (i >> 9) & 1;
    int q36 = i >> 10;
    int o = mt * 16 + (l & 15);
    int c = ((q36 & 3) << 5) + ((l >> 4) << 3) + j;
    int t = q36 >> 2;
    float v = 0.f;
    if (o < 18)      v = offw[(o * CIN + c) * 9 + t];
    else if (o < 27) v = modw[((o - 18) * CIN + c) * 9 + t];
    wCi[i] = f2bf(v);
}

// ---------------------------------------------------------------------------
// Prep 3: NCHW -> NHWC fp32 transpose of x.
//   xT[((b*128 + y)*128 + x)*128 + c]
// ---------------------------------------------------------------------------
__global__ __launch_bounds__(256) void xt_kernel(
    const float* __restrict__ x, float* __restrict__ xT)
{
    __shared__ float ls[32][132];
    const int tid = threadIdx.x;
    const int bz = blockIdx.x;                // b*512 + y*4 + cg
    const int cg = bz & 3;
    const int y  = (bz >> 2) & 127;
    const int b  = bz >> 9;
    {
        int c  = tid >> 3;                    // 0..31
        int x0 = (tid & 7) << 4;              // 0,16,..,112
        const float* src = x + (((size_t)(b * CIN + (cg << 5) + c)) << 14) + (y << 7) + x0;
#pragma unroll
        for (int k = 0; k < 4; ++k)
            *(f32x4*)&ls[c][x0 + 4 * k] = *(const f32x4*)(src + 4 * k);
    }
    __syncthreads();
    {
        int xc = tid >> 1;                    // 0..127
        int h  = tid & 1;                     // 16-ch half
        float v[16];
#pragma unroll
        for (int j = 0; j < 16; ++j) v[j] = ls[h * 16 + j][xc];
        float* dst = xT + ((((size_t)((b << 7) + y) << 7) + xc) << 7) + (cg << 5) + (h << 4);
#pragma unroll
        for (int k = 0; k < 4; ++k) {
            f32x4 t = { v[4 * k], v[4 * k + 1], v[4 * k + 2], v[4 * k + 3] };
            *(f32x4*)(dst + 4 * k) = t;
        }
    }
}

// ---------------------------------------------------------------------------
// Kernel CT (NEW, replaces convpart + tables): implicit-GEMM offset/mod conv
// via MFMA + fused sampling-table epilogue.
// R5 counters: convpart 75 us, VALUBusy 51%, MfmaUtil 0 -- a 4.1 GFLOP conv
// on the scalar ALU (26 us floor) vs ~2 us on matrix cores.
// Block = one (b, y) row, 4 waves x 32 px. Wave: M=32 outs (27 used) x
// N=32 px, K=1152 (36 chunks: t=q36>>2, c-chunk=q36&3). B-fragments are
// 8 contiguous fp32 channels from NHWC xT -> v_cvt_pk_bf16_f32 pack.
// y-OOB taps skip uniformly; x-OOB lanes select 0. C goes through a
// wave-private padded LDS tile ([32][33]) to hand each lane a full
// 27-output pixel for the tables epilogue (identical math to R5 tables).
// ---------------------------------------------------------------------------
__global__ __launch_bounds__(256) void convtab_kernel(
    const float* __restrict__ xT, const unsigned short* __restrict__ wCi,
    const float* __restrict__ offb, const float* __restrict__ modb,
    unsigned int* __restrict__ pk_out, float4* __restrict__ w4_out)
{
    __shared__ float outs[4][32][33];
    const int tid = threadIdx.x;
    const int wave = tid >> 6;
    const int l = tid & 63;
    const int bid = blockIdx.x;               // b*128 + y
    const int b = bid >> 7;
    const int y = bid & 127;
    const int x0 = wave << 5;
    const float* xb = xT + ((size_t)b << 21);

    f32x4 acc[2][2];
#pragma unroll
    for (int i = 0; i < 2; ++i)
#pragma unroll
        for (int j = 0; j < 2; ++j) acc[i][j] = (f32x4){0.f, 0.f, 0.f, 0.f};

    const int lp = l & 15;                    // px within 16-tile
    const int q8 = (l >> 4) << 3;             // channel octet base

#pragma unroll 1
    for (int q36 = 0; q36 < 36; ++q36) {
        const int t  = q36 >> 2;
        const int c0 = (q36 & 3) << 5;
        const int ty = t / 3, tx = t - 3 * ty;
        const int yp = y + ty - 1;
        if (yp < 0 || yp >= HH) continue;     // wave-uniform skip

        const unsigned short* ap = wCi + (q36 << 10) + (l << 3);
        short8 af0 = *(const short8*)(ap);
        short8 af1 = *(const short8*)(ap + 512);

        short8 bf[2];
#pragma unroll
        for (int nt = 0; nt < 2; ++nt) {
            int xp = x0 + nt * 16 + lp + tx - 1;
            bool xin = (xp >= 0) && (xp < WW);
            const float* src = xb +
                ((((yp << 7) + (xin ? xp : 0)) << 7) + c0 + q8);
            f32x4 z = {0.f, 0.f, 0.f, 0.f};
            f32x4 lo = xin ? *(const f32x4*)src : z;
            f32x4 hi = xin ? *(const f32x4*)(src + 4) : z;
            union { unsigned int u[4]; short8 s8; } cv;
            asm("v_cvt_pk_bf16_f32 %0, %1, %2" : "=v"(cv.u[0]) : "v"(lo[0]), "v"(lo[1]));
            asm("v_cvt_pk_bf16_f32 %0, %1, %2" : "=v"(cv.u[1]) : "v"(lo[2]), "v"(lo[3]));
            asm("v_cvt_pk_bf16_f32 %0, %1, %2" : "=v"(cv.u[2]) : "v"(hi[0]), "v"(hi[1]));
            asm("v_cvt_pk_bf16_f32 %0, %1, %2" : "=v"(cv.u[3]) : "v"(hi[2]), "v"(hi[3]));
            bf[nt] = cv.s8;
        }
        acc[0][0] = __builtin_amdgcn_mfma_f32_16x16x32_bf16(af0, bf[0], acc[0][0], 0, 0, 0);
        acc[1][0] = __builtin_amdgcn_mfma_f32_16x16x32_bf16(af1, bf[0], acc[1][0], 0, 0, 0);
        acc[0][1] = __builtin_amdgcn_mfma_f32_16x16x32_bf16(af0, bf[1], acc[0][1], 0, 0, 0);
        acc[1][1] = __builtin_amdgcn_mfma_f32_16x16x32_bf16(af1, bf[1], acc[1][1], 0, 0, 0);
    }

    // C -> wave-private LDS: [px 0..31][o 0..31], pad 33 breaks bank aliasing
    float (*po)[33] = outs[wave];
#pragma unroll
    for (int mt = 0; mt < 2; ++mt)
#pragma unroll
        for (int nt = 0; nt < 2; ++nt)
#pragma unroll
            for (int r = 0; r < 4; ++r)
                po[nt * 16 + lp][mt * 16 + (l >> 4) * 4 + r] = acc[mt][nt][r];

    // wave-synchronous epilogue (same-wave LDS; no barrier needed)
    const int pxe = l & 31;
    const int xw = x0 + pxe;
    const float* pe = &outs[wave][pxe][0];
#pragma unroll 1
    for (int kk = (l >> 5); kk < 9; kk += 2) {
        float oy = pe[2 * kk]     + offb[2 * kk];
        float ox = pe[2 * kk + 1] + offb[2 * kk + 1];
        float mt_ = pe[18 + kk]   + modb[kk];

        float m = 2.f / (1.f + expf(-mt_));
        float py = (float)(y - 1 + kk / 3) + oy;
        float px = (float)(xw - 1 + kk % 3) + ox;
        float y0f = floorf(py), x0f = floorf(px);
        float wy = py - y0f, wx = px - x0f;
        int y0 = (int)y0f, x0i = (int)x0f;
        int y1 = y0 + 1, x1 = x0i + 1;
        float vy0 = (y0 >= 0 && y0 < HH) ? 1.f : 0.f;
        float vy1 = (y1 >= 0 && y1 < HH) ? 1.f : 0.f;
        float vx0 = (x0i >= 0 && x0i < WW) ? 1.f : 0.f;
        float vx1 = (x1 >= 0 && x1 < WW) ? 1.f : 0.f;
        float a  = m * (1.f - wy) * vy0;
        float bb = m * wy * vy1;
        float u  = (1.f - wx) * vx0;
        float vv = wx * vx1;
        int y0c = min(max(y0, 0), HH - 1), y1c = min(max(y1, 0), HH - 1);
        int x0c = min(max(x0i, 0), WW - 1), x1c = min(max(x1, 0), WW - 1);
        int cb = min(max(x0i, 0), WW - 2);
        float wl = ((x0c == cb) ? u : 0.f) + ((x1c == cb) ? vv : 0.f);
        float wr = ((x0c == cb + 1) ? u : 0.f) + ((x1c == cb + 1) ? vv : 0.f);
        unsigned int pkv = (unsigned)y0c | ((unsigned)y1c << 7) |
                           ((unsigned)cb << 14);
        int gid = ((b * 9 + kk) << 14) + (y << 7) + xw;
        pk_out[gid] = pkv;
        w4_out[gid] = make_float4(a * wl, a * wr, bb * wl, bb * wr);
    }
}

// ---------------------------------------------------------------------------
// Kernel G (R4 version restored -- R5's two-pass band split cost +18 us net):
// ideal-pattern coalesced gather. Wave loads ONE pixel-corner-row
// (y, cb..cb+1, ch0..127) = 1024 B contiguous per instr (lane i -> base+16i).
// Column blend via per-lane colf fma; column-sum via shfl_xor(32); repack
// through 1KB wave-private LDS (no barriers, wave-synchronous).
// ---------------------------------------------------------------------------
__global__ __launch_bounds__(256) void gather_kernel(
    const float* __restrict__ xT, const unsigned int* __restrict__ pk,
    const float4* __restrict__ w4, unsigned short* __restrict__ samp,
    int b0, int nb2)
{
    __shared__ unsigned char glds[4096];      // 4 waves x 1 KB
    const int tid = threadIdx.x;
    const int wave = tid >> 6;
    const int l = tid & 63;
    unsigned char* wb = glds + (wave << 10);

    const int F = blockIdx.x;
    const int band = F % nb2;                 // nb2 = nb*2 bands (XCD-aligned)
    const int s = F / nb2;                    // 0..255
    const int lb = band >> 1;
    const int b = b0 + lb;
    const int yh = band & 1;
    const int unit = s * 4 + wave;            // 0..1023
    const int h = unit & 1;                   // pixel-half of the 16-px group
    const int gb = unit >> 1;                 // 0..511
    const int row = yh * 64 + (gb >> 3);
    const int gx16 = gb & 7;
    const int g = (lb << 10) + (row << 3) + gx16;
    const float* xb = xT + ((size_t)b << 21);
    unsigned short* sg0 = samp + (((size_t)g * 36) << 9);
    const float colf = (l >= 32) ? 1.f : 0.f;

    // lane (l&7) holds the sampling table entry for its pixel of this wave's 8
    int gi = ((b * 9) << 14) + (row << 7) + (gx16 << 4) + (h << 3) + (l & 7);
    unsigned int tpk = pk[gi];
    float4 tw = w4[gi];

#pragma unroll 1
    for (int kk = 0; kk < 9; ++kk) {
        // prefetch next kk's tables (clamped at kk==8)
        int gin = gi + ((kk < 8) ? 16384 : 0);
        unsigned int tpkn = pk[gin];
        float4 twn = w4[gin];

#pragma unroll
        for (int st = 0; st < 2; ++st) {
            f32x4 r0[4], r1[4];
            float cw0[4], cw1[4];
#pragma unroll
            for (int p = 0; p < 4; ++p) {
                const int idx = st * 4 + p;
                unsigned int pv = __shfl(tpk, idx);
                float wx_ = __shfl(tw.x, idx);
                float wy_ = __shfl(tw.y, idx);
                float wz_ = __shfl(tw.z, idx);
                float ww_ = __shfl(tw.w, idx);
                cw0[p] = fmaf(wy_ - wx_, colf, wx_);   // row y0 col weight
                cw1[p] = fmaf(ww_ - wz_, colf, wz_);   // row y1 col weight
                const int y0c = pv & 127;
                const int y1c = (pv >> 7) & 127;
                const int cb  = pv >> 14;              // [0,126]
                const float* base0 = xb + ((((y0c << 7) + cb) << 7) + (l << 2));
                const float* base1 = xb + ((((y1c << 7) + cb) << 7) + (l << 2));
                r0[p] = *(const f32x4*)base0;
                r1[p] = *(const f32x4*)base1;
            }
#pragma unroll
            for (int p = 0; p < 4; ++p) {
                float res[4];
#pragma unroll
                for (int j = 0; j < 4; ++j) {
                    float t = r0[p][j] * cw0[p] + r1[p][j] * cw1[p];
                    res[j] = t + __shfl_xor(t, 32);    // add other column
                }
                unsigned int d0 = (unsigned int)f2bf(res[0]) |
                                  ((unsigned int)f2bf(res[1]) << 16);
                unsigned int d1 = (unsigned int)f2bf(res[2]) |
                                  ((unsigned int)f2bf(res[3]) << 16);
                uint2 dd; dd.x = d0; dd.y = d1;
                *(uint2*)(wb + (p << 8) + ((l & 31) << 3)) = dd;
            }
            // wave-synchronous repack: quad (l&31) -> octet chunks
            ushort8 chunk = *(ushort8*)(wb + ((l >> 4) << 8) + ((l & 15) << 4));
            const int px = (h << 3) + (st << 2) + (l >> 4); // pixel in group
            const int cc = (l & 15) >> 2;
            const int q  = l & 3;
            *(ushort8*)&sg0[((((kk << 2) + cc) << 6) + (q << 4) + px) << 3] =
                chunk;
        }
        tpk = tpkn; tw = twn;
        gi += 16384;
    }
}

// ---------------------------------------------------------------------------
// Kernel B: clean MFMA GEMM (R1 version -- NT reverted; it cost +45 us in R2).
// ---------------------------------------------------------------------------
__global__ __launch_bounds__(256) void dgemm_kernel(
    const unsigned short* __restrict__ wAi,
    const unsigned short* __restrict__ samp,
    float* __restrict__ out, int b0)
{
    const int tid = threadIdx.x;
    const int wave = tid >> 6;
    const int l = tid & 63;
    const int bx = blockIdx.x;
    const int lb = bx >> 8;
    const int b = b0 + lb;
    const int seg = bx & 255;
    const int pix0 = seg << 6;
    const unsigned short* sb =
        samp + (((size_t)((lb << 10) + (seg << 2)) * 36) << 9) + (l << 3);
    const int NTS = 36 << 9;                // nt stride in shorts

    f32x4 acc[4][4];
#pragma unroll
    for (int i = 0; i < 4; ++i)
#pragma unroll
        for (int j = 0; j < 4; ++j) acc[i][j] = (f32x4){0.f, 0.f, 0.f, 0.f};

    short8 bf[4], bfn[4];
#pragma unroll
    for (int nt = 0; nt < 4; ++nt)
        bf[nt] = *(const short8*)(sb + nt * NTS);

#pragma unroll 1
    for (int c36 = 0; c36 < 36; ++c36) {
        // A fragments (oldest in vmcnt order)
        const unsigned short* ap = wAi + (c36 << 13) + (wave << 11) + (l << 3);
        short8 af[4];
#pragma unroll
        for (int mt = 0; mt < 4; ++mt)
            af[mt] = *(const short8*)(ap + (mt << 9));

        // prefetch next chunk's B (stays in flight across MFMAs)
        int cn = (c36 < 35) ? c36 + 1 : 35;
#pragma unroll
        for (int nt = 0; nt < 4; ++nt)
            bfn[nt] = *(const short8*)(sb + nt * NTS + (cn << 9));

#pragma unroll
        for (int mt = 0; mt < 4; ++mt)
#pragma unroll
            for (int nt = 0; nt < 4; ++nt)
                acc[mt][nt] = __builtin_amdgcn_mfma_f32_16x16x32_bf16(
                    af[mt], bf[nt], acc[mt][nt], 0, 0, 0);

#pragma unroll
        for (int nt = 0; nt < 4; ++nt) bf[nt] = bfn[nt];
    }

    // epilogue: C/D col=lane&15 (=px), row=(lane>>4)*4+reg (verified R2-R4)
    const int crow = (l >> 4) * 4;
    const int pxl = pix0 + (l & 15);
#pragma unroll
    for (int mt = 0; mt < 4; ++mt) {
#pragma unroll
        for (int nt = 0; nt < 4; ++nt) {
#pragma unroll
            for (int r = 0; r < 4; ++r) {
                int o = wave * 64 + mt * 16 + crow + r;
                out[(((size_t)(b * COUT + o)) << 14) + pxl + nt * 16] =
                    acc[mt][nt][r];
            }
        }
    }
}

// ---------------------------------------------------------------------------
extern "C" void kernel_launch(void* const* d_in, const int* in_sizes, int n_in,
                              void* d_out, int out_size, void* d_ws, size_t ws_size,
                              hipStream_t stream)
{
    const float* x    = (const float*)d_in[0];
    const float* offw = (const float*)d_in[1];
    const float* offb = (const float*)d_in[2];
    const float* modw = (const float*)d_in[3];
    const float* modb = (const float*)d_in[4];
    const float* wgt  = (const float*)d_in[5];
    float* out = (float*)d_out;

    char* wsb = (char*)d_ws;
    unsigned int*   pkp = (unsigned int*)wsb;                      //  2,359,296 B
    float4*         w4p = (float4*)(wsb + 2359296);                //  9,437,184 B
    unsigned short* wAi = (unsigned short*)(wsb + 11796480);       //    589,824 B
    unsigned short* wCi = (unsigned short*)(wsb + 12386304);       //     73,728 B
    float*          xTp = (float*)(wsb + 12460032);                // 33,554,432 B (NHWC image)
    const size_t persistX = 12460032 + 33554432;                   // 46,014,464
    unsigned short* samp = (unsigned short*)(wsb + persistX);
    const size_t SAMP1 = 37748736;   // bytes per batch of samp

    int nb = 4;
    if (ws_size < persistX + 4 * SAMP1) nb = 2;
    if (ws_size < persistX + 2 * SAMP1) nb = 1;

    wimg_kernel<<<dim3(COUT * CIN * 9 / 256), 256, 0, stream>>>(wgt, wAi);
    wcimg_kernel<<<dim3(144), 256, 0, stream>>>(offw, modw, wCi);
    xt_kernel<<<dim3(NB * 128 * 4), 256, 0, stream>>>(x, xTp);
    convtab_kernel<<<dim3(NB * HH), 256, 0, stream>>>(
        xTp, wCi, offb, modb, pkp, w4p);

    for (int b0 = 0; b0 < NB; b0 += nb) {
        gather_kernel<<<dim3(nb * 512), 256, 0, stream>>>(
            xTp, pkp, w4p, samp, b0, nb * 2);
        dgemm_kernel<<<dim3(nb * 256), 256, 0, stream>>>(wAi, samp, out, b0);
    }
}

// Round 7
// 258.646 us; speedup vs baseline: 1.2976x; 1.0888x over previous
//
#include <hip/hip_runtime.h>
#include <hip/hip_bf16.h>
#include <math.h>

#define CIN 128
#define HH 128
#define WW 128
#define HWX (HH*WW)
#define COUT 256
#define NB 4

typedef __attribute__((ext_vector_type(8))) short short8;
typedef __attribute__((ext_vector_type(4))) float f32x4;
typedef __attribute__((ext_vector_type(8))) unsigned short ushort8;

__device__ __forceinline__ unsigned short f2bf(float f) {
    union { float f; unsigned int u; } c; c.f = f;
    unsigned int u = c.u + 0x7FFF + ((c.u >> 16) & 1);   // RNE
    return (unsigned short)(u >> 16);
}

// ---------------------------------------------------------------------------
// Prep 1: bf16 A-fragment image for the big GEMM (layout verified R2-R4).
//   L = ((c36*16 + mt)*64 + l)*8 + j ; o = mt*16+(l&15); c = cc*32+(l>>4)*8+j
// ---------------------------------------------------------------------------
__global__ __launch_bounds__(256) void wimg_kernel(
    const float* __restrict__ wgt, unsigned short* __restrict__ wAi)
{
    int i = blockIdx.x * 256 + threadIdx.x;   // < 294912
    int j  = i & 7;
    int l  = (i >> 3) & 63;
    int mt = (i >> 9) & 15;
    int cc = (i >> 13) & 3;
    int kk = i >> 15;
    int o = mt * 16 + (l & 15);
    int c = cc * 32 + (l >> 4) * 8 + j;
    wAi[i] = f2bf(wgt[(o * CIN + c) * 9 + kk]);
}

// ---------------------------------------------------------------------------
// Prep 2: bf16 A-fragment image for the offset/mod conv GEMM.
//   27 outputs padded to 32; K = t*128 + c, 36 chunks.
// ---------------------------------------------------------------------------
__global__ __launch_bounds__(256) void wcimg_kernel(
    const float* __restrict__ offw, const float* __restrict__ modw,
    unsigned short* __restrict__ wCi)
{
    int i = blockIdx.x * 256 + threadIdx.x;   // < 36864
    if (i >= 36864) return;
    int j   = i & 7;
    int l   = (i >> 3) & 63;
    int mt  = (i >> 9) & 1;
    int q36 = i >> 10;
    int o = mt * 16 + (l & 15);
    int c = ((q36 & 3) << 5) + ((l >> 4) << 3) + j;
    int t = q36 >> 2;
    float v = 0.f;
    if (o < 18)      v = offw[(o * CIN + c) * 9 + t];
    else if (o < 27) v = modw[((o - 18) * CIN + c) * 9 + t];
    wCi[i] = f2bf(v);
}

// ---------------------------------------------------------------------------
// Prep 3: NCHW -> NHWC fp32 transpose of x.
//   xT[((b*128 + y)*128 + x)*128 + c]
// ---------------------------------------------------------------------------
__global__ __launch_bounds__(256) void xt_kernel(
    const float* __restrict__ x, float* __restrict__ xT)
{
    __shared__ float ls[32][132];
    const int tid = threadIdx.x;
    const int bz = blockIdx.x;                // b*512 + y*4 + cg
    const int cg = bz & 3;
    const int y  = (bz >> 2) & 127;
    const int b  = bz >> 9;
    {
        int c  = tid >> 3;                    // 0..31
        int x0 = (tid & 7) << 4;              // 0,16,..,112
        const float* src = x + (((size_t)(b * CIN + (cg << 5) + c)) << 14) + (y << 7) + x0;
#pragma unroll
        for (int k = 0; k < 4; ++k)
            *(f32x4*)&ls[c][x0 + 4 * k] = *(const f32x4*)(src + 4 * k);
    }
    __syncthreads();
    {
        int xc = tid >> 1;                    // 0..127
        int h  = tid & 1;                     // 16-ch half
        float v[16];
#pragma unroll
        for (int j = 0; j < 16; ++j) v[j] = ls[h * 16 + j][xc];
        float* dst = xT + ((((size_t)((b << 7) + y) << 7) + xc) << 7) + (cg << 5) + (h << 4);
#pragma unroll
        for (int k = 0; k < 4; ++k) {
            f32x4 t = { v[4 * k], v[4 * k + 1], v[4 * k + 2], v[4 * k + 3] };
            *(f32x4*)(dst + 4 * k) = t;
        }
    }
}

// ---------------------------------------------------------------------------
// Kernel CT: implicit-GEMM offset/mod conv via MFMA + fused sampling tables.
// (unchanged from R6 -- replaced convpart+tables, verified)
// ---------------------------------------------------------------------------
__global__ __launch_bounds__(256) void convtab_kernel(
    const float* __restrict__ xT, const unsigned short* __restrict__ wCi,
    const float* __restrict__ offb, const float* __restrict__ modb,
    unsigned int* __restrict__ pk_out, float4* __restrict__ w4_out)
{
    __shared__ float outs[4][32][33];
    const int tid = threadIdx.x;
    const int wave = tid >> 6;
    const int l = tid & 63;
    const int bid = blockIdx.x;               // b*128 + y
    const int b = bid >> 7;
    const int y = bid & 127;
    const int x0 = wave << 5;
    const float* xb = xT + ((size_t)b << 21);

    f32x4 acc[2][2];
#pragma unroll
    for (int i = 0; i < 2; ++i)
#pragma unroll
        for (int j = 0; j < 2; ++j) acc[i][j] = (f32x4){0.f, 0.f, 0.f, 0.f};

    const int lp = l & 15;                    // px within 16-tile
    const int q8 = (l >> 4) << 3;             // channel octet base

#pragma unroll 1
    for (int q36 = 0; q36 < 36; ++q36) {
        const int t  = q36 >> 2;
        const int c0 = (q36 & 3) << 5;
        const int ty = t / 3, tx = t - 3 * ty;
        const int yp = y + ty - 1;
        if (yp < 0 || yp >= HH) continue;     // wave-uniform skip

        const unsigned short* ap = wCi + (q36 << 10) + (l << 3);
        short8 af0 = *(const short8*)(ap);
        short8 af1 = *(const short8*)(ap + 512);

        short8 bf[2];
#pragma unroll
        for (int nt = 0; nt < 2; ++nt) {
            int xp = x0 + nt * 16 + lp + tx - 1;
            bool xin = (xp >= 0) && (xp < WW);
            const float* src = xb +
                ((((yp << 7) + (xin ? xp : 0)) << 7) + c0 + q8);
            f32x4 z = {0.f, 0.f, 0.f, 0.f};
            f32x4 lo = xin ? *(const f32x4*)src : z;
            f32x4 hi = xin ? *(const f32x4*)(src + 4) : z;
            union { unsigned int u[4]; short8 s8; } cv;
            asm("v_cvt_pk_bf16_f32 %0, %1, %2" : "=v"(cv.u[0]) : "v"(lo[0]), "v"(lo[1]));
            asm("v_cvt_pk_bf16_f32 %0, %1, %2" : "=v"(cv.u[1]) : "v"(lo[2]), "v"(lo[3]));
            asm("v_cvt_pk_bf16_f32 %0, %1, %2" : "=v"(cv.u[2]) : "v"(hi[0]), "v"(hi[1]));
            asm("v_cvt_pk_bf16_f32 %0, %1, %2" : "=v"(cv.u[3]) : "v"(hi[2]), "v"(hi[3]));
            bf[nt] = cv.s8;
        }
        acc[0][0] = __builtin_amdgcn_mfma_f32_16x16x32_bf16(af0, bf[0], acc[0][0], 0, 0, 0);
        acc[1][0] = __builtin_amdgcn_mfma_f32_16x16x32_bf16(af1, bf[0], acc[1][0], 0, 0, 0);
        acc[0][1] = __builtin_amdgcn_mfma_f32_16x16x32_bf16(af0, bf[1], acc[0][1], 0, 0, 0);
        acc[1][1] = __builtin_amdgcn_mfma_f32_16x16x32_bf16(af1, bf[1], acc[1][1], 0, 0, 0);
    }

    float (*po)[33] = outs[wave];
#pragma unroll
    for (int mt = 0; mt < 2; ++mt)
#pragma unroll
        for (int nt = 0; nt < 2; ++nt)
#pragma unroll
            for (int r = 0; r < 4; ++r)
                po[nt * 16 + lp][mt * 16 + (l >> 4) * 4 + r] = acc[mt][nt][r];

    const int pxe = l & 31;
    const int xw = x0 + pxe;
    const float* pe = &outs[wave][pxe][0];
#pragma unroll 1
    for (int kk = (l >> 5); kk < 9; kk += 2) {
        float oy = pe[2 * kk]     + offb[2 * kk];
        float ox = pe[2 * kk + 1] + offb[2 * kk + 1];
        float mt_ = pe[18 + kk]   + modb[kk];

        float m = 2.f / (1.f + expf(-mt_));
        float py = (float)(y - 1 + kk / 3) + oy;
        float px = (float)(xw - 1 + kk % 3) + ox;
        float y0f = floorf(py), x0f = floorf(px);
        float wy = py - y0f, wx = px - x0f;
        int y0 = (int)y0f, x0i = (int)x0f;
        int y1 = y0 + 1, x1 = x0i + 1;
        float vy0 = (y0 >= 0 && y0 < HH) ? 1.f : 0.f;
        float vy1 = (y1 >= 0 && y1 < HH) ? 1.f : 0.f;
        float vx0 = (x0i >= 0 && x0i < WW) ? 1.f : 0.f;
        float vx1 = (x1 >= 0 && x1 < WW) ? 1.f : 0.f;
        float a  = m * (1.f - wy) * vy0;
        float bb = m * wy * vy1;
        float u  = (1.f - wx) * vx0;
        float vv = wx * vx1;
        int y0c = min(max(y0, 0), HH - 1), y1c = min(max(y1, 0), HH - 1);
        int x0c = min(max(x0i, 0), WW - 1), x1c = min(max(x1, 0), WW - 1);
        int cb = min(max(x0i, 0), WW - 2);
        float wl = ((x0c == cb) ? u : 0.f) + ((x1c == cb) ? vv : 0.f);
        float wr = ((x0c == cb + 1) ? u : 0.f) + ((x1c == cb + 1) ? vv : 0.f);
        unsigned int pkv = (unsigned)y0c | ((unsigned)y1c << 7) |
                           ((unsigned)cb << 14);
        int gid = ((b * 9 + kk) << 14) + (y << 7) + xw;
        pk_out[gid] = pkv;
        w4_out[gid] = make_float4(a * wl, a * wr, bb * wl, bb * wr);
    }
}

// ---------------------------------------------------------------------------
// Kernel F (NEW, replaces gather + dgemm): fused gather->MFMA GEMM.
// Kills the 147 MB samp HBM write + 147 MB read-back. Block = 64 px (half
// row) x 256 Cout, 4 waves. Per K-chunk kk (K=128): each wave PRODUCES its
// 16-px group's B-fragments with the verified R4 gather math (1 KB ideal-
// pattern loads, colf blend, shfl_xor(32) col-sum, bounce repack) straight
// into a 16 KB double-buffered LDS B-tile; barrier; each wave consumes all
// 4 nt fragments for its 64-Cout rows (64 MFMA/wave/kk). LDS chunk layout
// == verified samp chunk layout. XCD-banded block swizzle: XCD x gets
// S in [128x,128x+128) -> sliding ~2.2 MB xT row window, L2-resident
// (fixes R4's 130 MB re-fetch without R5's pass serialization).
// cvt_pk == f2bf (both RNE) -> bit-identical output.
// ---------------------------------------------------------------------------
__global__ __launch_bounds__(256, 2) void fused_kernel(
    const float* __restrict__ xT, const unsigned short* __restrict__ wAi,
    const unsigned int* __restrict__ pk, const float4* __restrict__ w4,
    float* __restrict__ out)
{
    __shared__ unsigned short Blds[2][4][4][512];   // [buf][cc][nt][lane*8+j]
    __shared__ unsigned char bounce[4][1024];       // per-wave repack scratch

    const int tid = threadIdx.x;
    const int wv = tid >> 6;
    const int l = tid & 63;
    const int bx = blockIdx.x;
    const int S = ((bx & 7) << 7) + (bx >> 3);      // XCD banding (1024 blks)
    const int lb = S >> 8;                          // batch
    const int seg = S & 255;
    const int y = seg >> 1;
    const int x0 = (seg & 1) << 6;
    const float* xb = xT + ((size_t)lb << 21);
    unsigned char* wb = bounce[wv];
    const float colf = (l >= 32) ? 1.f : 0.f;

    // table entries for this wave's 16 px (lane l&15 holds pixel l&15)
    int gi = ((lb * 9) << 14) + (y << 7) + x0 + (wv << 4) + (l & 15);
    unsigned int tpk = pk[gi];
    float4 tw = w4[gi];

    f32x4 acc[4][4];
#pragma unroll
    for (int i = 0; i < 4; ++i)
#pragma unroll
        for (int j = 0; j < 4; ++j) acc[i][j] = (f32x4){0.f, 0.f, 0.f, 0.f};

    auto produce = [&](int kk, int buf) {
        int gin = gi + ((kk < 8) ? 16384 : 0);      // prefetch next kk tables
        unsigned int tpkn = pk[gin];
        float4 twn = w4[gin];
#pragma unroll
        for (int st = 0; st < 4; ++st) {
            f32x4 r0[4], r1[4];
            float cw0[4], cw1[4];
#pragma unroll
            for (int p = 0; p < 4; ++p) {
                const int idx = st * 4 + p;
                unsigned int pv = __shfl(tpk, idx);
                float wxx = __shfl(tw.x, idx);
                float wyy = __shfl(tw.y, idx);
                float wzz = __shfl(tw.z, idx);
                float www = __shfl(tw.w, idx);
                cw0[p] = fmaf(wyy - wxx, colf, wxx);   // row y0 col weight
                cw1[p] = fmaf(www - wzz, colf, wzz);   // row y1 col weight
                const int y0c = pv & 127;
                const int y1c = (pv >> 7) & 127;
                const int cb  = pv >> 14;              // [0,126]
                r0[p] = *(const f32x4*)(xb + ((((y0c << 7) + cb) << 7) + (l << 2)));
                r1[p] = *(const f32x4*)(xb + ((((y1c << 7) + cb) << 7) + (l << 2)));
            }
#pragma unroll
            for (int p = 0; p < 4; ++p) {
                float res[4];
#pragma unroll
                for (int j = 0; j < 4; ++j) {
                    float t = r0[p][j] * cw0[p] + r1[p][j] * cw1[p];
                    res[j] = t + __shfl_xor(t, 32);    // add other column
                }
                unsigned int d0, d1;
                asm("v_cvt_pk_bf16_f32 %0, %1, %2" : "=v"(d0) : "v"(res[0]), "v"(res[1]));
                asm("v_cvt_pk_bf16_f32 %0, %1, %2" : "=v"(d1) : "v"(res[2]), "v"(res[3]));
                uint2 dd; dd.x = d0; dd.y = d1;
                *(uint2*)(wb + (p << 8) + ((l & 31) << 3)) = dd;
            }
            // wave-synchronous repack: bounce -> fragment-ordered LDS chunk
            ushort8 chunk = *(ushort8*)(wb + ((l >> 4) << 8) + ((l & 15) << 4));
            const int pxg = (st << 2) + (l >> 4);      // pixel 0..15 in group
            const int cc = (l & 15) >> 2;
            const int q  = l & 3;
            *(ushort8*)&Blds[buf][cc][wv][((q << 4) + pxg) << 3] = chunk;
        }
        tpk = tpkn; tw = twn; gi += 16384;
    };

    produce(0, 0);
    __syncthreads();

#pragma unroll 1
    for (int kk = 0; kk < 9; ++kk) {
        const int buf = kk & 1;
        if (kk < 8) produce(kk + 1, buf ^ 1);
#pragma unroll
        for (int cc = 0; cc < 4; ++cc) {
            const unsigned short* ap =
                wAi + (((kk << 2) + cc) << 13) + (wv << 11) + (l << 3);
            short8 af[4];
#pragma unroll
            for (int mt = 0; mt < 4; ++mt)
                af[mt] = *(const short8*)(ap + (mt << 9));
            short8 bfr[4];
#pragma unroll
            for (int nt = 0; nt < 4; ++nt)
                bfr[nt] = *(const short8*)&Blds[buf][cc][nt][l << 3];
#pragma unroll
            for (int mt = 0; mt < 4; ++mt)
#pragma unroll
                for (int nt = 0; nt < 4; ++nt)
                    acc[mt][nt] = __builtin_amdgcn_mfma_f32_16x16x32_bf16(
                        af[mt], bfr[nt], acc[mt][nt], 0, 0, 0);
        }
        __syncthreads();
    }

    // epilogue: C/D col=lane&15 (=px), row=(lane>>4)*4+reg (verified R2-R4)
    const int crow = (l >> 4) * 4;
    const int pxl = (seg << 6) + (l & 15);
#pragma unroll
    for (int mt = 0; mt < 4; ++mt) {
#pragma unroll
        for (int nt = 0; nt < 4; ++nt) {
#pragma unroll
            for (int r = 0; r < 4; ++r) {
                int o = wv * 64 + mt * 16 + crow + r;
                out[(((size_t)(lb * COUT + o)) << 14) + pxl + nt * 16] =
                    acc[mt][nt][r];
            }
        }
    }
}

// ---------------------------------------------------------------------------
extern "C" void kernel_launch(void* const* d_in, const int* in_sizes, int n_in,
                              void* d_out, int out_size, void* d_ws, size_t ws_size,
                              hipStream_t stream)
{
    const float* x    = (const float*)d_in[0];
    const float* offw = (const float*)d_in[1];
    const float* offb = (const float*)d_in[2];
    const float* modw = (const float*)d_in[3];
    const float* modb = (const float*)d_in[4];
    const float* wgt  = (const float*)d_in[5];
    float* out = (float*)d_out;

    char* wsb = (char*)d_ws;
    unsigned int*   pkp = (unsigned int*)wsb;                      //  2,359,296 B
    float4*         w4p = (float4*)(wsb + 2359296);                //  9,437,184 B
    unsigned short* wAi = (unsigned short*)(wsb + 11796480);       //    589,824 B
    unsigned short* wCi = (unsigned short*)(wsb + 12386304);       //     73,728 B
    float*          xTp = (float*)(wsb + 12460032);                // 33,554,432 B
    // total persistent: 46,014,464 B -- no samp buffer anymore

    wimg_kernel<<<dim3(COUT * CIN * 9 / 256), 256, 0, stream>>>(wgt, wAi);
    wcimg_kernel<<<dim3(144), 256, 0, stream>>>(offw, modw, wCi);
    xt_kernel<<<dim3(NB * 128 * 4), 256, 0, stream>>>(x, xTp);
    convtab_kernel<<<dim3(NB * HH), 256, 0, stream>>>(
        xTp, wCi, offb, modb, pkp, w4p);
    fused_kernel<<<dim3(NB * 256), 256, 0, stream>>>(
        xTp, wAi, pkp, w4p, out);
}

// Round 10
// 231.901 us; speedup vs baseline: 1.4472x; 1.1153x over previous
//
#include <hip/hip_runtime.h>
#include <hip/hip_bf16.h>
#include <math.h>

#define CIN 128
#define HH 128
#define WW 128
#define HWX (HH*WW)
#define COUT 256
#define NB 4

typedef __attribute__((ext_vector_type(8))) short short8;
typedef __attribute__((ext_vector_type(4))) float f32x4;
typedef __attribute__((ext_vector_type(8))) unsigned short ushort8;

__device__ __forceinline__ unsigned short f2bf(float f) {
    union { float f; unsigned int u; } c; c.f = f;
    unsigned int u = c.u + 0x7FFF + ((c.u >> 16) & 1);   // RNE
    return (unsigned short)(u >> 16);
}

// ---------------------------------------------------------------------------
// Prep (merged: xt + wimg + wcimg -- one launch instead of three).
// Block roles by blockIdx: [0,2048) xt, [2048,3200) wimg, [3200,3344) wcimg.
// ---------------------------------------------------------------------------
__global__ __launch_bounds__(256) void prep_kernel(
    const float* __restrict__ x, const float* __restrict__ wgt,
    const float* __restrict__ offw, const float* __restrict__ modw,
    float* __restrict__ xT, unsigned short* __restrict__ wAi,
    unsigned short* __restrict__ wCi)
{
    const int tid = threadIdx.x;
    const int bxg = blockIdx.x;

    if (bxg < 2048) {
        // ---- xt: NCHW -> NHWC fp32 transpose ----
        __shared__ float ls[32][132];
        const int bz = bxg;                   // b*512 + y*4 + cg
        const int cg = bz & 3;
        const int y  = (bz >> 2) & 127;
        const int b  = bz >> 9;
        {
            int c  = tid >> 3;                // 0..31
            int x0 = (tid & 7) << 4;
            const float* src = x + (((size_t)(b * CIN + (cg << 5) + c)) << 14) + (y << 7) + x0;
#pragma unroll
            for (int k = 0; k < 4; ++k)
                *(f32x4*)&ls[c][x0 + 4 * k] = *(const f32x4*)(src + 4 * k);
        }
        __syncthreads();
        {
            int xc = tid >> 1;
            int h  = tid & 1;
            float v[16];
#pragma unroll
            for (int j = 0; j < 16; ++j) v[j] = ls[h * 16 + j][xc];
            float* dst = xT + ((((size_t)((b << 7) + y) << 7) + xc) << 7) + (cg << 5) + (h << 4);
#pragma unroll
            for (int k = 0; k < 4; ++k) {
                f32x4 t = { v[4 * k], v[4 * k + 1], v[4 * k + 2], v[4 * k + 3] };
                *(f32x4*)(dst + 4 * k) = t;
            }
        }
    } else if (bxg < 3200) {
        // ---- wimg: bf16 A-fragment image for the big GEMM ----
        int i = (bxg - 2048) * 256 + tid;     // < 294912
        int j  = i & 7;
        int l  = (i >> 3) & 63;
        int mt = (i >> 9) & 15;
        int cc = (i >> 13) & 3;
        int kk = i >> 15;
        int o = mt * 16 + (l & 15);
        int c = cc * 32 + (l >> 4) * 8 + j;
        wAi[i] = f2bf(wgt[(o * CIN + c) * 9 + kk]);
    } else {
        // ---- wcimg: bf16 A-fragment image for offset/mod conv ----
        int i = (bxg - 3200) * 256 + tid;     // < 36864
        if (i < 36864) {
            int j   = i & 7;
            int l   = (i >> 3) & 63;
            int mt  = (i >> 9) & 1;
            int q36 = i >> 10;
            int o = mt * 16 + (l & 15);
            int c = ((q36 & 3) << 5) + ((l >> 4) << 3) + j;
            int t = q36 >> 2;
            float v = 0.f;
            if (o < 18)      v = offw[(o * CIN + c) * 9 + t];
            else if (o < 27) v = modw[((o - 18) * CIN + c) * 9 + t];
            wCi[i] = f2bf(v);
        }
    }
}

// ---------------------------------------------------------------------------
// Kernel CT: implicit-GEMM offset/mod conv via MFMA + fused sampling tables.
// (unchanged from R6/R7 -- verified)
// ---------------------------------------------------------------------------
__global__ __launch_bounds__(256) void convtab_kernel(
    const float* __restrict__ xT, const unsigned short* __restrict__ wCi,
    const float* __restrict__ offb, const float* __restrict__ modb,
    unsigned int* __restrict__ pk_out, float4* __restrict__ w4_out)
{
    __shared__ float outs[4][32][33];
    const int tid = threadIdx.x;
    const int wave = tid >> 6;
    const int l = tid & 63;
    const int bid = blockIdx.x;               // b*128 + y
    const int b = bid >> 7;
    const int y = bid & 127;
    const int x0 = wave << 5;
    const float* xb = xT + ((size_t)b << 21);

    f32x4 acc[2][2];
#pragma unroll
    for (int i = 0; i < 2; ++i)
#pragma unroll
        for (int j = 0; j < 2; ++j) acc[i][j] = (f32x4){0.f, 0.f, 0.f, 0.f};

    const int lp = l & 15;
    const int q8 = (l >> 4) << 3;

#pragma unroll 1
    for (int q36 = 0; q36 < 36; ++q36) {
        const int t  = q36 >> 2;
        const int c0 = (q36 & 3) << 5;
        const int ty = t / 3, tx = t - 3 * ty;
        const int yp = y + ty - 1;
        if (yp < 0 || yp >= HH) continue;     // wave-uniform skip

        const unsigned short* ap = wCi + (q36 << 10) + (l << 3);
        short8 af0 = *(const short8*)(ap);
        short8 af1 = *(const short8*)(ap + 512);

        short8 bf[2];
#pragma unroll
        for (int nt = 0; nt < 2; ++nt) {
            int xp = x0 + nt * 16 + lp + tx - 1;
            bool xin = (xp >= 0) && (xp < WW);
            const float* src = xb +
                ((((yp << 7) + (xin ? xp : 0)) << 7) + c0 + q8);
            f32x4 z = {0.f, 0.f, 0.f, 0.f};
            f32x4 lo = xin ? *(const f32x4*)src : z;
            f32x4 hi = xin ? *(const f32x4*)(src + 4) : z;
            union { unsigned int u[4]; short8 s8; } cv;
            asm("v_cvt_pk_bf16_f32 %0, %1, %2" : "=v"(cv.u[0]) : "v"(lo[0]), "v"(lo[1]));
            asm("v_cvt_pk_bf16_f32 %0, %1, %2" : "=v"(cv.u[1]) : "v"(lo[2]), "v"(lo[3]));
            asm("v_cvt_pk_bf16_f32 %0, %1, %2" : "=v"(cv.u[2]) : "v"(hi[0]), "v"(hi[1]));
            asm("v_cvt_pk_bf16_f32 %0, %1, %2" : "=v"(cv.u[3]) : "v"(hi[2]), "v"(hi[3]));
            bf[nt] = cv.s8;
        }
        acc[0][0] = __builtin_amdgcn_mfma_f32_16x16x32_bf16(af0, bf[0], acc[0][0], 0, 0, 0);
        acc[1][0] = __builtin_amdgcn_mfma_f32_16x16x32_bf16(af1, bf[0], acc[1][0], 0, 0, 0);
        acc[0][1] = __builtin_amdgcn_mfma_f32_16x16x32_bf16(af0, bf[1], acc[0][1], 0, 0, 0);
        acc[1][1] = __builtin_amdgcn_mfma_f32_16x16x32_bf16(af1, bf[1], acc[1][1], 0, 0, 0);
    }

    float (*po)[33] = outs[wave];
#pragma unroll
    for (int mt = 0; mt < 2; ++mt)
#pragma unroll
        for (int nt = 0; nt < 2; ++nt)
#pragma unroll
            for (int r = 0; r < 4; ++r)
                po[nt * 16 + lp][mt * 16 + (l >> 4) * 4 + r] = acc[mt][nt][r];

    const int pxe = l & 31;
    const int xw = x0 + pxe;
    const float* pe = &outs[wave][pxe][0];
#pragma unroll 1
    for (int kk = (l >> 5); kk < 9; kk += 2) {
        float oy = pe[2 * kk]     + offb[2 * kk];
        float ox = pe[2 * kk + 1] + offb[2 * kk + 1];
        float mt_ = pe[18 + kk]   + modb[kk];

        float m = 2.f / (1.f + expf(-mt_));
        float py = (float)(y - 1 + kk / 3) + oy;
        float px = (float)(xw - 1 + kk % 3) + ox;
        float y0f = floorf(py), x0f = floorf(px);
        float wy = py - y0f, wx = px - x0f;
        int y0 = (int)y0f, x0i = (int)x0f;
        int y1 = y0 + 1, x1 = x0i + 1;
        float vy0 = (y0 >= 0 && y0 < HH) ? 1.f : 0.f;
        float vy1 = (y1 >= 0 && y1 < HH) ? 1.f : 0.f;
        float vx0 = (x0i >= 0 && x0i < WW) ? 1.f : 0.f;
        float vx1 = (x1 >= 0 && x1 < WW) ? 1.f : 0.f;
        float a  = m * (1.f - wy) * vy0;
        float bb = m * wy * vy1;
        float u  = (1.f - wx) * vx0;
        float vv = wx * vx1;
        int y0c = min(max(y0, 0), HH - 1), y1c = min(max(y1, 0), HH - 1);
        int x0c = min(max(x0i, 0), WW - 1), x1c = min(max(x1, 0), WW - 1);
        int cb = min(max(x0i, 0), WW - 2);
        float wl = ((x0c == cb) ? u : 0.f) + ((x1c == cb) ? vv : 0.f);
        float wr = ((x0c == cb + 1) ? u : 0.f) + ((x1c == cb + 1) ? vv : 0.f);
        unsigned int pkv = (unsigned)y0c | ((unsigned)y1c << 7) |
                           ((unsigned)cb << 14);
        int gid = ((b * 9 + kk) << 14) + (y << 7) + xw;
        pk_out[gid] = pkv;
        w4_out[gid] = make_float4(a * wl, a * wr, bb * wl, bb * wr);
    }
}

// ---------------------------------------------------------------------------
// Kernel F (R10 = R9 resubmit after infra failure; R8 design + stride fix):
// fused gather->MFMA GEMM, de-conflicted + pipelined.
// Blds[2][4][4][512] (ushort): per-buffer stride 16384 BYTES (4*4*512*2).
// Design: (1) per-block tables in LDS (broadcast ds_reads replace 20
// shfls/st), (2) blend stores go DIRECT to Blds with XOR swizzle
// byte ^ (q<<5) ^ ((cc&1)<<4) -- write 2-way (free), read conflict-free,
// (3) per-st interleave: af loads -> bfr ds_reads -> next-kk staging loads
// -> setprio(1) 16xMFMA setprio(0) -> blend+swizzled store.
// ---------------------------------------------------------------------------
__global__ __launch_bounds__(256, 2) void fused_kernel(
    const float* __restrict__ xT, const unsigned short* __restrict__ wAi,
    const unsigned int* __restrict__ pk, const float4* __restrict__ w4,
    float* __restrict__ out)
{
    __shared__ unsigned short Blds[2][4][4][512];   // 32 KB total, 16 KB/buf
    __shared__ unsigned int tpk_l[576];             // 9 kk x 64 px
    __shared__ float4 tw_l[576];

    const int tid = threadIdx.x;
    const int wv = tid >> 6;
    const int l = tid & 63;
    const int bx = blockIdx.x;
    const int S = ((bx & 7) << 7) + (bx >> 3);      // XCD banding (1024 blks)
    const int lb = S >> 8;                          // batch
    const int seg = S & 255;
    const int y = seg >> 1;
    const int x0 = (seg & 1) << 6;
    const float* xb = xT + ((size_t)lb << 21);
    const float colf = (l >= 32) ? 1.f : 0.f;
    unsigned char* BB = (unsigned char*)&Blds[0][0][0][0];

    // ---- preload this block's tables (64 px x 9 kk) ----
    {
        const int base = ((lb * 9) << 14) + (y << 7) + x0;
        for (int e = tid; e < 576; e += 256) {
            tpk_l[e] = pk[base + ((e >> 6) << 14) + (e & 63)];
            tw_l[e]  = w4[base + ((e >> 6) << 14) + (e & 63)];
        }
    }
    __syncthreads();

    f32x4 acc[4][4];
#pragma unroll
    for (int i = 0; i < 4; ++i)
#pragma unroll
        for (int j = 0; j < 4; ++j) acc[i][j] = (f32x4){0.f, 0.f, 0.f, 0.f};

    // ---- prologue: stage kk=0 into buf 0 ----
#pragma unroll
    for (int st = 0; st < 4; ++st) {
        f32x4 r0[4], r1[4];
        float cw0[4], cw1[4];
#pragma unroll
        for (int p = 0; p < 4; ++p) {
            int e = (wv << 4) + (st << 2) + p;
            unsigned int pv = tpk_l[e];
            float4 twv = tw_l[e];
            cw0[p] = fmaf(twv.y - twv.x, colf, twv.x);
            cw1[p] = fmaf(twv.w - twv.z, colf, twv.z);
            const int y0c = pv & 127, y1c = (pv >> 7) & 127, cb = pv >> 14;
            r0[p] = *(const f32x4*)(xb + ((((y0c << 7) + cb) << 7) + (l << 2)));
            r1[p] = *(const f32x4*)(xb + ((((y1c << 7) + cb) << 7) + (l << 2)));
        }
#pragma unroll
        for (int p = 0; p < 4; ++p) {
            float res[4];
#pragma unroll
            for (int j = 0; j < 4; ++j) {
                float t = r0[p][j] * cw0[p] + r1[p][j] * cw1[p];
                res[j] = t + __shfl_xor(t, 32);
            }
            unsigned int d0, d1;
            asm("v_cvt_pk_bf16_f32 %0, %1, %2" : "=v"(d0) : "v"(res[0]), "v"(res[1]));
            asm("v_cvt_pk_bf16_f32 %0, %1, %2" : "=v"(d1) : "v"(res[2]), "v"(res[3]));
            if (l < 32) {
                int q  = (l >> 1) & 3;
                int h  = l & 1;
                int cw = l >> 3;
                int pxg = (st << 2) + p;
                int off = cw * 4096 + wv * 1024 +
                          (((q << 8) + (pxg << 4) + (h << 3)) ^
                           ((q << 5) ^ ((cw & 1) << 4)));
                uint2 dd; dd.x = d0; dd.y = d1;
                *(uint2*)(BB + off) = dd;
            }
        }
    }
    __syncthreads();

    // ---- main loop: MFMA(kk, buf) interleaved with staging(kk+1, buf^1) ----
#pragma unroll 1
    for (int kk = 0; kk < 9; ++kk) {
        const int buf = kk & 1;
        const int nbo = (buf ^ 1) * 16384;          // 16 KB per-buffer stride
#pragma unroll
        for (int st = 0; st < 4; ++st) {
            const int cc = st;
            // A fragments first (oldest vmcnt -> MFMA waits only on these)
            const unsigned short* ap =
                wAi + (((kk << 2) + cc) << 13) + (wv << 11) + (l << 3);
            short8 af[4];
#pragma unroll
            for (int mt = 0; mt < 4; ++mt)
                af[mt] = *(const short8*)(ap + (mt << 9));
            // B fragments from LDS (swizzled)
            short8 bfr[4];
            {
                int ro = ((((l >> 4) << 8) + ((l & 15) << 4)) ^
                          (((l >> 4) << 5) ^ ((cc & 1) << 4)));
                const unsigned char* rb = BB + buf * 16384 + cc * 4096 + ro;
#pragma unroll
                for (int nt = 0; nt < 4; ++nt)
                    bfr[nt] = *(const short8*)(rb + nt * 1024);
            }
            // staging loads for kk+1 (issued before MFMA, consumed after)
            f32x4 r0[4], r1[4];
            float cw0[4], cw1[4];
            if (kk < 8) {
#pragma unroll
                for (int p = 0; p < 4; ++p) {
                    int e = ((kk + 1) << 6) + (wv << 4) + (st << 2) + p;
                    unsigned int pv = tpk_l[e];
                    float4 twv = tw_l[e];
                    cw0[p] = fmaf(twv.y - twv.x, colf, twv.x);
                    cw1[p] = fmaf(twv.w - twv.z, colf, twv.z);
                    const int y0c = pv & 127, y1c = (pv >> 7) & 127, cb = pv >> 14;
                    r0[p] = *(const f32x4*)(xb + ((((y0c << 7) + cb) << 7) + (l << 2)));
                    r1[p] = *(const f32x4*)(xb + ((((y1c << 7) + cb) << 7) + (l << 2)));
                }
            }
            // MFMA cluster
            __builtin_amdgcn_s_setprio(1);
#pragma unroll
            for (int mt = 0; mt < 4; ++mt)
#pragma unroll
                for (int nt = 0; nt < 4; ++nt)
                    acc[mt][nt] = __builtin_amdgcn_mfma_f32_16x16x32_bf16(
                        af[mt], bfr[nt], acc[mt][nt], 0, 0, 0);
            __builtin_amdgcn_s_setprio(0);
            // blend + swizzled direct store into buf^1
            if (kk < 8) {
#pragma unroll
                for (int p = 0; p < 4; ++p) {
                    float res[4];
#pragma unroll
                    for (int j = 0; j < 4; ++j) {
                        float t = r0[p][j] * cw0[p] + r1[p][j] * cw1[p];
                        res[j] = t + __shfl_xor(t, 32);
                    }
                    unsigned int d0, d1;
                    asm("v_cvt_pk_bf16_f32 %0, %1, %2" : "=v"(d0) : "v"(res[0]), "v"(res[1]));
                    asm("v_cvt_pk_bf16_f32 %0, %1, %2" : "=v"(d1) : "v"(res[2]), "v"(res[3]));
                    if (l < 32) {
                        int q  = (l >> 1) & 3;
                        int h  = l & 1;
                        int cw = l >> 3;
                        int pxg = (st << 2) + p;
                        int off = nbo + cw * 4096 + wv * 1024 +
                                  (((q << 8) + (pxg << 4) + (h << 3)) ^
                                   ((q << 5) ^ ((cw & 1) << 4)));
                        uint2 dd; dd.x = d0; dd.y = d1;
                        *(uint2*)(BB + off) = dd;
                    }
                }
            }
        }
        __syncthreads();
    }

    // epilogue: C/D col=lane&15 (=px), row=(lane>>4)*4+reg (verified R2-R4)
    const int crow = (l >> 4) * 4;
    const int pxl = (seg << 6) + (l & 15);
#pragma unroll
    for (int mt = 0; mt < 4; ++mt) {
#pragma unroll
        for (int nt = 0; nt < 4; ++nt) {
#pragma unroll
            for (int r = 0; r < 4; ++r) {
                int o = wv * 64 + mt * 16 + crow + r;
                out[(((size_t)(lb * COUT + o)) << 14) + pxl + nt * 16] =
                    acc[mt][nt][r];
            }
        }
    }
}

// ---------------------------------------------------------------------------
extern "C" void kernel_launch(void* const* d_in, const int* in_sizes, int n_in,
                              void* d_out, int out_size, void* d_ws, size_t ws_size,
                              hipStream_t stream)
{
    const float* x    = (const float*)d_in[0];
    const float* offw = (const float*)d_in[1];
    const float* offb = (const float*)d_in[2];
    const float* modw = (const float*)d_in[3];
    const float* modb = (const float*)d_in[4];
    const float* wgt  = (const float*)d_in[5];
    float* out = (float*)d_out;

    char* wsb = (char*)d_ws;
    unsigned int*   pkp = (unsigned int*)wsb;                      //  2,359,296 B
    float4*         w4p = (float4*)(wsb + 2359296);                //  9,437,184 B
    unsigned short* wAi = (unsigned short*)(wsb + 11796480);       //    589,824 B
    unsigned short* wCi = (unsigned short*)(wsb + 12386304);       //     73,728 B
    float*          xTp = (float*)(wsb + 12460032);                // 33,554,432 B

    prep_kernel<<<dim3(3344), 256, 0, stream>>>(
        x, wgt, offw, modw, xTp, wAi, wCi);
    convtab_kernel<<<dim3(NB * HH), 256, 0, stream>>>(
        xTp, wCi, offb, modb, pkp, w4p);
    fused_kernel<<<dim3(NB * 256), 256, 0, stream>>>(
        xTp, wAi, pkp, w4p, out);
}